// Round 1
// 713.365 us; speedup vs baseline: 1.0006x; 1.0006x over previous
//
#include <hip/hip_runtime.h>
#include <math.h>

#define B_   8
#define Hs   56
#define Ws   56
#define Cc   768
#define NHh  12
#define HDd  64
#define Nt   3137
#define HW_  3136
#define C3   2304
#define SCALE 0.125f
#define Mrows (B_ * Nt)        // 25096
#define Mpad  (99 * 256)       // 25344 (256-row tiles)

typedef _Float16 half8  __attribute__((ext_vector_type(8)));
typedef _Float16 half4  __attribute__((ext_vector_type(4)));
typedef _Float16 half2_ __attribute__((ext_vector_type(2)));
typedef float floatx4 __attribute__((ext_vector_type(4)));

__device__ inline float fdot2f(half2_ a, half2_ b, float c) {
#if __has_builtin(__builtin_amdgcn_fdot2)
    return __builtin_amdgcn_fdot2(a, b, c, false);
#else
    return fmaf((float)a.x, (float)b.x, fmaf((float)a.y, (float)b.y, c));
#endif
}

// ---------------- scratch (__device__ globals) -----------------------------
__device__ _Float16 g_qkvh[(size_t)Mrows * C3];          // fp16 qkv (115 MB)
__device__ float    g_Ocol[(size_t)B_ * NHh * HW_ * HDd];
__device__ float    g_mcol[(size_t)B_ * NHh * HW_];
__device__ float    g_lcol[(size_t)B_ * NHh * HW_];
__device__ _Float16 g_xh[(size_t)Mpad * Cc];
__device__ _Float16 g_attH[(size_t)Mpad * Cc];
__device__ _Float16 g_WqkvT[(size_t)C3 * Cc];
__device__ _Float16 g_WprojT[(size_t)Cc * Cc];
__device__ float    g_clsP[(size_t)B_ * NHh * 4 * 66];   // per-partial: m,l,O[64]

// ---------------- fp32 -> fp16 convert -------------------------------------
__global__ __launch_bounds__(256) void cvt_f16(
    const float* __restrict__ in, _Float16* __restrict__ out, int n4)
{
    for (int i = blockIdx.x * 256 + threadIdx.x; i < n4; i += gridDim.x * 256) {
        float4 v = ((const float4*)in)[i];
        half4 h = { (_Float16)v.x, (_Float16)v.y, (_Float16)v.z, (_Float16)v.w };
        ((half4*)out)[i] = h;
    }
}

// ---------------- fp32 [R][Cq] -> fp16 transposed [Cq][R] ------------------
__global__ __launch_bounds__(256) void transpose_f16(
    const float* __restrict__ in, _Float16* __restrict__ out, int R, int Cq)
{
    __shared__ float t[32][33];
    const int c0 = blockIdx.x * 32, r0 = blockIdx.y * 32;
    const int tx = threadIdx.x & 31, ty = threadIdx.x >> 5;
#pragma unroll
    for (int i = 0; i < 32; i += 8)
        t[ty + i][tx] = in[(size_t)(r0 + ty + i) * Cq + c0 + tx];
    __syncthreads();
#pragma unroll
    for (int i = 0; i < 32; i += 8)
        out[(size_t)(c0 + ty + i) * R + r0 + tx] = (_Float16)t[tx][ty + i];
}

// ---------------------------------------------------------------------------
// fp16 MFMA GEMM: C[M,Nd] = A[Mpad,K] @ Bt[Nd,K]^T (+bias).
// R1: 256x256 tile, BK=64, 512 thr (8 waves 2Mx4N), double-buffered LDS
// (128 KiB) with 2-phase pipeline: STAGE(next) issued before compute(cur),
// single barrier per K-tile (T3-minimum recipe). Staging keeps the verified
// unit-swizzled layout (conflict-free b128 fragment reads by construction).
// Swapped-operand MFMA so the epilogue stores half4/float4 along n.
// 16-row panel swizzle of block index for L2 reuse of the B panel.
// ---------------------------------------------------------------------------
template <typename OutT>
__global__ __launch_bounds__(512, 2) void gemm_f16(
    const _Float16* __restrict__ A, const _Float16* __restrict__ Bt,
    const float* __restrict__ bias, OutT* __restrict__ Cm,
    int M, int Nd, int K)
{
    __shared__ _Float16 lds[2][2][256 * 64];   // [buf][A/B][16384 halfs]
    const int tid = threadIdx.x;
    const int wave = tid >> 6, lane = tid & 63;
    const int wm = wave & 1, wn = wave >> 1;

    // panel swizzle: 16 row-blocks per panel, col-major within panel
    const int bid = blockIdx.y * gridDim.x + blockIdx.x;
    const int perPanel = gridDim.x * 16;
    const int panel = bid / perPanel;
    const int rowsIn = min(16, (int)gridDim.y - panel * 16);
    const int rem = bid - panel * perPanel;
    const int by = panel * 16 + rem % rowsIn;
    const int bx = rem / rowsIn;
    const int mBase = by * 256, nBase = bx * 256;

    // staging: 2048 16B-units per matrix per K-tile; thread handles
    // u = i*512 + tid, i in [0,4). u -> row m=(u>>7)*16+(u&15), kc=(u>>4)&7,
    // LDS byte offset u*16. i-increment is wave-uniform (+64 rows).
    const int mU  = ((tid >> 7) << 4) + (tid & 15);
    const int kcU = (tid >> 4) & 7;
    const _Float16* ga = A  + (size_t)(mBase + mU) * K + kcU * 8;
    const _Float16* gb = Bt + (size_t)(nBase + mU) * K + kcU * 8;
    const size_t strideI = (size_t)64 * K;

    auto stage = [&](int buf, int kt) {
        const _Float16* gaK = ga + (size_t)kt * 64;
        const _Float16* gbK = gb + (size_t)kt * 64;
        _Float16* lA = &lds[buf][0][wave * 512];
        _Float16* lB = &lds[buf][1][wave * 512];
#pragma unroll
        for (int i = 0; i < 4; ++i) {
            __builtin_amdgcn_global_load_lds(
                (const __attribute__((address_space(1))) void*)(gaK + i * strideI),
                (__attribute__((address_space(3))) void*)(lA + i * 4096), 16, 0, 0);
            __builtin_amdgcn_global_load_lds(
                (const __attribute__((address_space(1))) void*)(gbK + i * strideI),
                (__attribute__((address_space(3))) void*)(lB + i * 4096), 16, 0, 0);
        }
    };

    // fragment offsets (halfs): group g holds 16 rows x 64 k = 1024 halfs;
    // within: kk*512 + (lane>>4)*128 + (lane&15)*8. A group = wm*8+mi,
    // B group = wn*4+ni.
    const int aoff = wm * 8192 + (lane >> 4) * 128 + (lane & 15) * 8;
    const int boff = wn * 4096 + (lane >> 4) * 128 + (lane & 15) * 8;

    floatx4 acc[8][4] = {};

    auto compute = [&](int buf) {
#pragma unroll
        for (int kk = 0; kk < 2; ++kk) {
            half8 a[8], b[4];
#pragma unroll
            for (int mi = 0; mi < 8; ++mi)
                a[mi] = *(const half8*)&lds[buf][0][aoff + kk * 512 + mi * 1024];
#pragma unroll
            for (int ni = 0; ni < 4; ++ni)
                b[ni] = *(const half8*)&lds[buf][1][boff + kk * 512 + ni * 1024];
            // swapped operands: rows of D <- n (from Bt), cols of D <- m
#pragma unroll
            for (int mi = 0; mi < 8; ++mi)
#pragma unroll
                for (int ni = 0; ni < 4; ++ni)
                    acc[mi][ni] = __builtin_amdgcn_mfma_f32_16x16x32_f16(
                        b[ni], a[mi], acc[mi][ni], 0, 0, 0);
        }
    };

    const int NT = K >> 6;           // 12 K-tiles of 64
    stage(0, 0);
    __syncthreads();                 // drain prologue stage (vmcnt0 at barrier)
    int cur = 0;
    for (int t = 0; t < NT - 1; ++t) {
        stage(cur ^ 1, t + 1);       // issue next tile BEFORE compute
        compute(cur);                // ds_read + MFMA hide the stage latency
        __syncthreads();             // reads of cur done + stage of cur^1 landed
        cur ^= 1;
    }
    compute(cur);                    // last tile, no prefetch

    // lane's m = col side (lane&15), n = row side ((lane>>4)*4 + r)
    const int mLane = mBase + wm * 128 + (lane & 15);
    const int nLane = nBase + wn * 64 + ((lane >> 4) << 2);
#pragma unroll
    for (int ni = 0; ni < 4; ++ni) {
        const int n0 = nLane + ni * 16;
        float4 bv = bias ? *(const float4*)&bias[n0] : make_float4(0.f, 0.f, 0.f, 0.f);
#pragma unroll
        for (int mi = 0; mi < 8; ++mi) {
            const int m = mLane + mi * 16;
            if (m < M) {
                floatx4 v = acc[mi][ni];
                if constexpr (sizeof(OutT) == 2) {
                    half4 h = { (_Float16)(v[0] + bv.x), (_Float16)(v[1] + bv.y),
                                (_Float16)(v[2] + bv.z), (_Float16)(v[3] + bv.w) };
                    *(half4*)&Cm[(size_t)m * Nd + n0] = h;
                } else {
                    float4 o = make_float4(v[0] + bv.x, v[1] + bv.y, v[2] + bv.z, v[3] + bv.w);
                    *(float4*)&Cm[(size_t)m * Nd + n0] = o;
                }
            }
        }
    }
}

// ---------------------------------------------------------------------------
// Column attention partials: block (w,nh,b), 64 thr. K fp16 LDS + fdot2,
// V fp32 LDS. Online softmax, unnormalized partial out.
// ---------------------------------------------------------------------------
__global__ __launch_bounds__(64) void col_attn(
    const _Float16* __restrict__ qkvh, float* __restrict__ Ocol,
    float* __restrict__ mcol, float* __restrict__ lcol)
{
    const int w = blockIdx.x, nh = blockIdx.y, b = blockIdx.z;
    __shared__ __align__(16) _Float16 Kh[57 * HDd];
    __shared__ float Vf[57 * HDd];
    const int tid = threadIdx.x;

    for (int e = tid; e < 57 * 8; e += 64) {
        int j = e >> 3, c = e & 7;
        int n = (j == 0) ? 0 : ((j - 1) * Ws + w + 1);
        const _Float16* base = qkvh + (size_t)(b * Nt + n) * C3 + nh * HDd + c * 8;
        *(half8*)&Kh[j * HDd + c * 8] = *(const half8*)(base + Cc);
        half8 vv = *(const half8*)(base + 2 * Cc);
        float4 lo = { (float)vv[0], (float)vv[1], (float)vv[2], (float)vv[3] };
        float4 hi = { (float)vv[4], (float)vv[5], (float)vv[6], (float)vv[7] };
        *(float4*)&Vf[j * HDd + c * 8] = lo;
        *(float4*)&Vf[j * HDd + c * 8 + 4] = hi;
    }
    __syncthreads();

    if (tid < Hs) {
        const int h = tid;
        const int n = h * Ws + w + 1;
        const _Float16* qp = qkvh + (size_t)(b * Nt + n) * C3 + nh * HDd;
        half8 q8[8];
#pragma unroll
        for (int c = 0; c < 8; ++c) q8[c] = ((const half8*)qp)[c];

        float m = -INFINITY, l = 0.f;
        float4 O4[16] = {};

        for (int j = 0; j <= Hs; ++j) {
            const half8* kp = (const half8*)&Kh[j * HDd];
            float s0 = 0.f, s1 = 0.f, s2 = 0.f, s3 = 0.f;
#pragma unroll
            for (int c = 0; c < 8; ++c) {
                half8 kk = kp[c];
                const half2_* k2 = (const half2_*)&kk;
                const half2_* qq = (const half2_*)&q8[c];
                s0 = fdot2f(qq[0], k2[0], s0);
                s1 = fdot2f(qq[1], k2[1], s1);
                s2 = fdot2f(qq[2], k2[2], s2);
                s3 = fdot2f(qq[3], k2[3], s3);
            }
            float s = ((s0 + s1) + (s2 + s3)) * SCALE;
            float mn = fmaxf(m, s);
            float corr = __expf(m - mn);
            float p = __expf(s - mn);
            l = l * corr + p;
            const float4* vp = (const float4*)&Vf[j * HDd];
#pragma unroll
            for (int d4 = 0; d4 < 16; ++d4) {
                float4 vv = vp[d4];
                O4[d4].x = fmaf(O4[d4].x, corr, p * vv.x);
                O4[d4].y = fmaf(O4[d4].y, corr, p * vv.y);
                O4[d4].z = fmaf(O4[d4].z, corr, p * vv.z);
                O4[d4].w = fmaf(O4[d4].w, corr, p * vv.w);
            }
            m = mn;
        }
        const size_t qi = (size_t)((b * NHh + nh) * HW_ + h * Ws + w);
        mcol[qi] = m;
        lcol[qi] = l;
#pragma unroll
        for (int d4 = 0; d4 < 16; ++d4)
            *(float4*)&Ocol[qi * HDd + d4 * 4] = O4[d4];
    }
}

// ---------------------------------------------------------------------------
// Row attention + merge -> attH (fp16)
// ---------------------------------------------------------------------------
__global__ __launch_bounds__(64) void row_attn_merge(
    const _Float16* __restrict__ qkvh, const float* __restrict__ Ocol,
    const float* __restrict__ mcol, const float* __restrict__ lcol,
    _Float16* __restrict__ attH)
{
    const int h = blockIdx.x, nh = blockIdx.y, b = blockIdx.z;
    __shared__ __align__(16) _Float16 Kh[Ws * HDd];
    __shared__ float Vf[Ws * HDd];
    const int tid = threadIdx.x;

    for (int e = tid; e < Ws * 8; e += 64) {
        int j = e >> 3, c = e & 7;
        int n = h * Ws + j + 1;
        const _Float16* base = qkvh + (size_t)(b * Nt + n) * C3 + nh * HDd + c * 8;
        *(half8*)&Kh[j * HDd + c * 8] = *(const half8*)(base + Cc);
        half8 vv = *(const half8*)(base + 2 * Cc);
        float4 lo = { (float)vv[0], (float)vv[1], (float)vv[2], (float)vv[3] };
        float4 hi = { (float)vv[4], (float)vv[5], (float)vv[6], (float)vv[7] };
        *(float4*)&Vf[j * HDd + c * 8] = lo;
        *(float4*)&Vf[j * HDd + c * 8 + 4] = hi;
    }
    __syncthreads();

    if (tid < Ws) {
        const int w = tid;
        const int n = h * Ws + w + 1;
        const _Float16* qp = qkvh + (size_t)(b * Nt + n) * C3 + nh * HDd;
        half8 q8[8];
#pragma unroll
        for (int c = 0; c < 8; ++c) q8[c] = ((const half8*)qp)[c];

        float m = -INFINITY, l = 0.f;
        float4 O4[16] = {};

        for (int j = 0; j < Ws; ++j) {
            if (j == w) continue;
            const half8* kp = (const half8*)&Kh[j * HDd];
            float s0 = 0.f, s1 = 0.f, s2 = 0.f, s3 = 0.f;
#pragma unroll
            for (int c = 0; c < 8; ++c) {
                half8 kk = kp[c];
                const half2_* k2 = (const half2_*)&kk;
                const half2_* qq = (const half2_*)&q8[c];
                s0 = fdot2f(qq[0], k2[0], s0);
                s1 = fdot2f(qq[1], k2[1], s1);
                s2 = fdot2f(qq[2], k2[2], s2);
                s3 = fdot2f(qq[3], k2[3], s3);
            }
            float s = ((s0 + s1) + (s2 + s3)) * SCALE;
            float mn = fmaxf(m, s);
            float corr = __expf(m - mn);
            float p = __expf(s - mn);
            l = l * corr + p;
            const float4* vp = (const float4*)&Vf[j * HDd];
#pragma unroll
            for (int d4 = 0; d4 < 16; ++d4) {
                float4 vv = vp[d4];
                O4[d4].x = fmaf(O4[d4].x, corr, p * vv.x);
                O4[d4].y = fmaf(O4[d4].y, corr, p * vv.y);
                O4[d4].z = fmaf(O4[d4].z, corr, p * vv.z);
                O4[d4].w = fmaf(O4[d4].w, corr, p * vv.w);
            }
            m = mn;
        }

        const size_t qi = (size_t)((b * NHh + nh) * HW_ + h * Ws + w);
        const float mc = mcol[qi], lc = lcol[qi];
        const float mn = fmaxf(mc, m);
        const float fc = __expf(mc - mn);
        const float fr = __expf(m - mn);
        const float inv = 1.f / (lc * fc + l * fr);
        _Float16* op = attH + (size_t)(b * Nt + n) * Cc + nh * HDd;
        const float* ocp = Ocol + qi * HDd;
#pragma unroll
        for (int d4 = 0; d4 < 16; ++d4) {
            float4 oc = *(const float4*)(ocp + d4 * 4);
            half4 r = { (_Float16)((oc.x * fc + O4[d4].x * fr) * inv),
                        (_Float16)((oc.y * fc + O4[d4].y * fr) * inv),
                        (_Float16)((oc.z * fc + O4[d4].z * fr) * inv),
                        (_Float16)((oc.w * fc + O4[d4].w * fr) * inv) };
            *(half4*)(op + d4 * 4) = r;
        }
    }
}

// ---------------------------------------------------------------------------
// Cls-token attention, 4-way key-split for occupancy. Partial (m,l,O) per
// (b,nh,s); merged by cls_merge.
// ---------------------------------------------------------------------------
__global__ __launch_bounds__(1024) void cls_part(
    const _Float16* __restrict__ qkvh, float* __restrict__ P)
{
    const int nh = blockIdx.x, b = blockIdx.y, sidx = blockIdx.z;
    const int j0 = sidx * 785, j1 = min(Nt, j0 + 785);
    const int tid = threadIdx.x;
    const int lane = tid & 63, wv = tid >> 6;

    const float qd = (float)qkvh[(size_t)(b * Nt) * C3 + nh * HDd + lane];
    float m = -INFINITY, l = 0.f, Od = 0.f;

    for (int j = j0 + wv; j < j1; j += 16) {
        const _Float16* base = qkvh + (size_t)(b * Nt + j) * C3 + nh * HDd;
        float prod = qd * (float)base[Cc + lane];
#pragma unroll
        for (int off = 32; off >= 1; off >>= 1)
            prod += __shfl_xor(prod, off, 64);
        float s = prod * SCALE;
        float mn = fmaxf(m, s);
        float corr = __expf(m - mn);
        float p = __expf(s - mn);
        l = l * corr + p;
        Od = fmaf(Od, corr, p * (float)base[2 * Cc + lane]);
        m = mn;
    }

    __shared__ float sm[16], sl[16], sO[16][64];
    if (lane == 0) { sm[wv] = m; sl[wv] = l; }
    sO[wv][lane] = Od;
    __syncthreads();

    if (tid < 64) {
        float M2 = sm[0];
#pragma unroll
        for (int i = 1; i < 16; ++i) M2 = fmaxf(M2, sm[i]);
        float L = 0.f, OO = 0.f;
#pragma unroll
        for (int i = 0; i < 16; ++i) {
            float f = __expf(sm[i] - M2);
            L += sl[i] * f;
            OO += sO[i][tid] * f;
        }
        float* pp = P + (size_t)((b * NHh + nh) * 4 + sidx) * 66;
        if (tid == 0) { pp[0] = M2; pp[1] = L; }
        pp[2 + tid] = OO;
    }
}

__global__ __launch_bounds__(64) void cls_merge(
    const float* __restrict__ P, _Float16* __restrict__ attH)
{
    const int nh = blockIdx.x, b = blockIdx.y;
    const int tid = threadIdx.x;
    const float* p0 = P + (size_t)(b * NHh + nh) * 4 * 66;
    float M2 = fmaxf(fmaxf(p0[0], p0[66]), fmaxf(p0[132], p0[198]));
    float L = 0.f, OO = 0.f;
#pragma unroll
    for (int i = 0; i < 4; ++i) {
        const float* pp = p0 + i * 66;
        float f = __expf(pp[0] - M2);
        L += pp[1] * f;
        OO += pp[2 + tid] * f;
    }
    attH[(size_t)(b * Nt) * Cc + nh * HDd + tid] = (_Float16)(OO / L);
}

// ---------------------------------------------------------------------------
extern "C" void kernel_launch(void* const* d_in, const int* in_sizes, int n_in,
                              void* d_out, int out_size, void* d_ws, size_t ws_size,
                              hipStream_t stream)
{
    const float* x     = (const float*)d_in[0];
    const float* Wqkv  = (const float*)d_in[1];
    const float* Wproj = (const float*)d_in[2];
    const float* bproj = (const float*)d_in[3];
    float* out = (float*)d_out;

    _Float16* qkvh;   hipGetSymbolAddress((void**)&qkvh,   HIP_SYMBOL(g_qkvh));
    float*    Ocol;   hipGetSymbolAddress((void**)&Ocol,   HIP_SYMBOL(g_Ocol));
    float*    mcol;   hipGetSymbolAddress((void**)&mcol,   HIP_SYMBOL(g_mcol));
    float*    lcol;   hipGetSymbolAddress((void**)&lcol,   HIP_SYMBOL(g_lcol));
    _Float16* xh;     hipGetSymbolAddress((void**)&xh,     HIP_SYMBOL(g_xh));
    _Float16* attH;   hipGetSymbolAddress((void**)&attH,   HIP_SYMBOL(g_attH));
    _Float16* WqkvT;  hipGetSymbolAddress((void**)&WqkvT,  HIP_SYMBOL(g_WqkvT));
    _Float16* WprojT; hipGetSymbolAddress((void**)&WprojT, HIP_SYMBOL(g_WprojT));
    float*    clsP;   hipGetSymbolAddress((void**)&clsP,   HIP_SYMBOL(g_clsP));

    // 0) prep
    cvt_f16<<<4096, 256, 0, stream>>>(x, xh, (Mrows * Cc) / 4);
    transpose_f16<<<dim3(C3 / 32, Cc / 32), 256, 0, stream>>>(Wqkv, WqkvT, Cc, C3);
    transpose_f16<<<dim3(Cc / 32, Cc / 32), 256, 0, stream>>>(Wproj, WprojT, Cc, Cc);

    // 1) qkv = x @ W_qkv  (fp16 out)
    gemm_f16<_Float16><<<dim3(C3 / 256, Mpad / 256), 512, 0, stream>>>(
        xh, WqkvT, nullptr, qkvh, Mrows, C3, Cc);

    // 2) attention
    col_attn<<<dim3(Ws, NHh, B_), 64, 0, stream>>>(qkvh, Ocol, mcol, lcol);
    cls_part<<<dim3(NHh, B_, 4), 1024, 0, stream>>>(qkvh, clsP);
    cls_merge<<<dim3(NHh, B_), 64, 0, stream>>>(clsP, attH);
    row_attn_merge<<<dim3(Hs, NHh, B_), 64, 0, stream>>>(qkvh, Ocol, mcol, lcol, attH);

    // 3) out = attH @ W_proj + b_proj  (fp32 out)
    gemm_f16<float><<<dim3(Cc / 256, Mpad / 256), 512, 0, stream>>>(
        attH, WprojT, bproj, out, Mrows, Cc, Cc);
}

// Round 2
// 635.727 us; speedup vs baseline: 1.1228x; 1.1221x over previous
//
#include <hip/hip_runtime.h>
#include <math.h>

#define B_   8
#define Hs   56
#define Ws   56
#define Cc   768
#define NHh  12
#define HDd  64
#define Nt   3137
#define HW_  3136
#define C3   2304
#define SCALE 0.125f
#define Mrows (B_ * Nt)        // 25096
#define Mpad  (99 * 256)       // 25344 (256-row tiles)

typedef _Float16 half8  __attribute__((ext_vector_type(8)));
typedef _Float16 half4  __attribute__((ext_vector_type(4)));
typedef _Float16 half2_ __attribute__((ext_vector_type(2)));
typedef float floatx4 __attribute__((ext_vector_type(4)));

#define WAITV(N) asm volatile("s_waitcnt vmcnt(" #N ")" ::: "memory")
#define WAITL    asm volatile("s_waitcnt lgkmcnt(0)" ::: "memory")

__device__ __forceinline__ void barrier_mem() {
    asm volatile("" ::: "memory");
    __builtin_amdgcn_s_barrier();
    asm volatile("" ::: "memory");
}

__device__ inline float fdot2f(half2_ a, half2_ b, float c) {
#if __has_builtin(__builtin_amdgcn_fdot2)
    return __builtin_amdgcn_fdot2(a, b, c, false);
#else
    return fmaf((float)a.x, (float)b.x, fmaf((float)a.y, (float)b.y, c));
#endif
}

// ---------------- scratch (__device__ globals) -----------------------------
__device__ _Float16 g_qkvh[(size_t)Mrows * C3];          // fp16 qkv (115 MB)
__device__ float    g_Ocol[(size_t)B_ * NHh * HW_ * HDd];
__device__ float    g_mcol[(size_t)B_ * NHh * HW_];
__device__ float    g_lcol[(size_t)B_ * NHh * HW_];
__device__ _Float16 g_xh[(size_t)Mpad * Cc];
__device__ _Float16 g_attH[(size_t)Mpad * Cc];
__device__ _Float16 g_WqkvT[(size_t)C3 * Cc];
__device__ _Float16 g_WprojT[(size_t)Cc * Cc];
__device__ float    g_clsP[(size_t)B_ * NHh * 4 * 66];   // per-partial: m,l,O[64]

// ---------------- fp32 -> fp16 convert -------------------------------------
__global__ __launch_bounds__(256) void cvt_f16(
    const float* __restrict__ in, _Float16* __restrict__ out, int n4)
{
    for (int i = blockIdx.x * 256 + threadIdx.x; i < n4; i += gridDim.x * 256) {
        float4 v = ((const float4*)in)[i];
        half4 h = { (_Float16)v.x, (_Float16)v.y, (_Float16)v.z, (_Float16)v.w };
        ((half4*)out)[i] = h;
    }
}

// ---------------- fp32 [R][Cq] -> fp16 transposed [Cq][R] ------------------
__global__ __launch_bounds__(256) void transpose_f16(
    const float* __restrict__ in, _Float16* __restrict__ out, int R, int Cq)
{
    __shared__ float t[32][33];
    const int c0 = blockIdx.x * 32, r0 = blockIdx.y * 32;
    const int tx = threadIdx.x & 31, ty = threadIdx.x >> 5;
#pragma unroll
    for (int i = 0; i < 32; i += 8)
        t[ty + i][tx] = in[(size_t)(r0 + ty + i) * Cq + c0 + tx];
    __syncthreads();
#pragma unroll
    for (int i = 0; i < 32; i += 8)
        out[(size_t)(c0 + ty + i) * R + r0 + tx] = (_Float16)t[tx][ty + i];
}

// ---------------------------------------------------------------------------
// fp16 MFMA GEMM: C[M,Nd] = A[Mpad,K] @ Bt[Nd,K]^T (+bias).
// R2: 256x256 tile, BK=32, 512 thr (8 waves 2Mx4N). FOUR rotating 32 KiB LDS
// buffers, staging runs 3 K-tiles ahead with COUNTED vmcnt (steady state
// vmcnt(8): 2 tiles / 8 loads stay in flight across the barrier — T4).
// Per tile: lgkmcnt(0) -> vmcnt(N) -> s_barrier -> stage(t+3) -> ds_read+MFMA
// (T5 setprio around the MFMA cluster). Buffer freed by t-1's reads (drained
// by each wave's lgkmcnt(0) before the barrier) is re-staged for t+3.
// Epilogue: acc -> padded LDS C-tile -> fully-coalesced 16B/lane row stores
// (kills the 2.7-4x partial-line write amplification seen in R1 counters).
// 16-row panel swizzle of block index for L2 reuse of the B panel.
// ---------------------------------------------------------------------------
template <typename OutT>
__global__ __launch_bounds__(512, 2) void gemm_f16(
    const _Float16* __restrict__ A, const _Float16* __restrict__ Bt,
    const float* __restrict__ bias, OutT* __restrict__ Cm,
    int M, int Nd, int K)
{
    // main loop: 4 bufs x (A 16KB + B 16KB) = 128 KiB
    // epilogue:  fp16 [256][264] halfs = 132 KiB / fp32 [256][132] = 132 KiB
    __shared__ __align__(16) char smem[135168];
    const int tid = threadIdx.x;
    const int wave = tid >> 6, lane = tid & 63;
    const int wm = wave & 1, wn = wave >> 1;

    // panel swizzle: 16 row-blocks per panel, col-major within panel
    const int bid = blockIdx.y * gridDim.x + blockIdx.x;
    const int perPanel = gridDim.x * 16;
    const int panel = bid / perPanel;
    const int rowsIn = min(16, (int)gridDim.y - panel * 16);
    const int rem = bid - panel * perPanel;
    const int by = panel * 16 + rem % rowsIn;
    const int bx = rem / rowsIn;
    const int mBase = by * 256, nBase = bx * 256;

    // staging: per matrix per K-tile 1024 16B-units; thread handles
    // u = i*512 + tid, i in {0,1}. u -> row ((u>>6)<<4)+(u&15), kc=(u>>4)&3,
    // LDS byte offset u*16 (wave-uniform base + lane*16 => global_load_lds ok)
    const int mU  = ((tid >> 6) << 4) + (tid & 15);
    const int kcU = (tid >> 4) & 3;
    const _Float16* ga = A  + (size_t)(mBase + mU) * K + kcU * 8;
    const _Float16* gb = Bt + (size_t)(nBase + mU) * K + kcU * 8;
    const size_t strideI = (size_t)128 * K;

    auto stage = [&](int t) {
        const int buf = t & 3;
        const _Float16* gaK = ga + t * 32;
        const _Float16* gbK = gb + t * 32;
        char* base = smem + buf * 32768;
        _Float16* lA = (_Float16*)(base)          + wave * 512;
        _Float16* lB = (_Float16*)(base + 16384)  + wave * 512;
#pragma unroll
        for (int i = 0; i < 2; ++i) {
            __builtin_amdgcn_global_load_lds(
                (const __attribute__((address_space(1))) void*)(gaK + i * strideI),
                (__attribute__((address_space(3))) void*)(lA + i * 4096), 16, 0, 0);
            __builtin_amdgcn_global_load_lds(
                (const __attribute__((address_space(1))) void*)(gbK + i * strideI),
                (__attribute__((address_space(3))) void*)(lB + i * 4096), 16, 0, 0);
        }
    };

    // fragment offset within a 16-row group (512 halfs): conflict-free b128
    const int foff = (lane >> 4) * 128 + (lane & 15) * 8;

    floatx4 acc[8][4] = {};

    auto compute = [&](int buf) {
        const _Float16* bufA = (const _Float16*)(smem + buf * 32768);
        const _Float16* bufB = (const _Float16*)(smem + buf * 32768 + 16384);
        half8 a[8], b[4];
#pragma unroll
        for (int mi = 0; mi < 8; ++mi)
            a[mi] = *(const half8*)&bufA[(wm * 8 + mi) * 512 + foff];
#pragma unroll
        for (int ni = 0; ni < 4; ++ni)
            b[ni] = *(const half8*)&bufB[(wn * 4 + ni) * 512 + foff];
        __builtin_amdgcn_s_setprio(1);
        // swapped operands: rows of D <- n (from Bt), cols of D <- m
#pragma unroll
        for (int mi = 0; mi < 8; ++mi)
#pragma unroll
            for (int ni = 0; ni < 4; ++ni)
                acc[mi][ni] = __builtin_amdgcn_mfma_f32_16x16x32_f16(
                    b[ni], a[mi], acc[mi][ni], 0, 0, 0);
        __builtin_amdgcn_s_setprio(0);
    };

    const int NT = K >> 5;           // 24 K-tiles of 32
    stage(0); stage(1); stage(2);    // depth-3 prologue (12 loads in flight)

    for (int t = 0; t < NT; ++t) {
        WAITL;                        // my ds_reads of tile t-1 retired
        if (t < NT - 2)      { WAITV(8); }   // tile t landed; 2 tiles in flight
        else if (t == NT - 2){ WAITV(4); }
        else                 { WAITV(0); }
        barrier_mem();                // everyone: tile t ready, buf[t-1] free
        if (t + 3 < NT) stage(t + 3);
        compute(t & 3);
    }
    WAITL;
    barrier_mem();                    // LDS buffers free for epilogue reuse

    const int mlBase = wm * 128 + (lane & 15);
    const int nlBase = wn * 64 + ((lane >> 4) << 2);

    if constexpr (sizeof(OutT) == 2) {
        _Float16* Ch = (_Float16*)smem;          // [256][264] padded
#pragma unroll
        for (int ni = 0; ni < 4; ++ni) {
            const int nl = nlBase + ni * 16;
#pragma unroll
            for (int mi = 0; mi < 8; ++mi) {
                const int ml = mlBase + mi * 16;
                floatx4 v = acc[mi][ni];
                half4 h = { (_Float16)v[0], (_Float16)v[1],
                            (_Float16)v[2], (_Float16)v[3] };
                *(half4*)&Ch[ml * 264 + nl] = h;
            }
        }
        barrier_mem();
#pragma unroll
        for (int i = 0; i < 16; ++i) {
            const int f = i * 512 + tid;
            const int row = f >> 5, u = f & 31;
            const int gm = mBase + row;
            if (gm < M)
                *(half8*)&Cm[(size_t)gm * Nd + nBase + u * 8] =
                    *(const half8*)&Ch[row * 264 + u * 8];
        }
    } else {
        float* Cf = (float*)smem;                // [256][132] padded
#pragma unroll
        for (int nh = 0; nh < 2; ++nh) {
            barrier_mem();                       // prev pass reads done
            if ((wn >> 1) == nh) {
#pragma unroll
                for (int ni = 0; ni < 4; ++ni) {
                    const int n0 = nBase + wn * 64 + ((lane >> 4) << 2) + ni * 16;
                    float4 bv = bias ? *(const float4*)&bias[n0]
                                     : make_float4(0.f, 0.f, 0.f, 0.f);
                    const int nl = (wn & 1) * 64 + ((lane >> 4) << 2) + ni * 16;
#pragma unroll
                    for (int mi = 0; mi < 8; ++mi) {
                        const int ml = mlBase + mi * 16;
                        floatx4 v = acc[mi][ni];
                        float4 o = make_float4(v[0] + bv.x, v[1] + bv.y,
                                               v[2] + bv.z, v[3] + bv.w);
                        *(float4*)&Cf[ml * 132 + nl] = o;
                    }
                }
            }
            barrier_mem();
#pragma unroll
            for (int i = 0; i < 16; ++i) {
                const int f = i * 512 + tid;
                const int row = f >> 5, u = f & 31;
                const int gm = mBase + row;
                if (gm < M)
                    *(float4*)&Cm[(size_t)gm * Nd + nBase + nh * 128 + u * 4] =
                        *(const float4*)&Cf[row * 132 + u * 4];
            }
        }
    }
}

// ---------------------------------------------------------------------------
// Column attention partials: block (w,nh,b), 64 thr. K fp16 LDS + fdot2,
// V fp32 LDS. Online softmax, unnormalized partial out.
// ---------------------------------------------------------------------------
__global__ __launch_bounds__(64) void col_attn(
    const _Float16* __restrict__ qkvh, float* __restrict__ Ocol,
    float* __restrict__ mcol, float* __restrict__ lcol)
{
    const int w = blockIdx.x, nh = blockIdx.y, b = blockIdx.z;
    __shared__ __align__(16) _Float16 Kh[57 * HDd];
    __shared__ float Vf[57 * HDd];
    const int tid = threadIdx.x;

    for (int e = tid; e < 57 * 8; e += 64) {
        int j = e >> 3, c = e & 7;
        int n = (j == 0) ? 0 : ((j - 1) * Ws + w + 1);
        const _Float16* base = qkvh + (size_t)(b * Nt + n) * C3 + nh * HDd + c * 8;
        *(half8*)&Kh[j * HDd + c * 8] = *(const half8*)(base + Cc);
        half8 vv = *(const half8*)(base + 2 * Cc);
        float4 lo = { (float)vv[0], (float)vv[1], (float)vv[2], (float)vv[3] };
        float4 hi = { (float)vv[4], (float)vv[5], (float)vv[6], (float)vv[7] };
        *(float4*)&Vf[j * HDd + c * 8] = lo;
        *(float4*)&Vf[j * HDd + c * 8 + 4] = hi;
    }
    __syncthreads();

    if (tid < Hs) {
        const int h = tid;
        const int n = h * Ws + w + 1;
        const _Float16* qp = qkvh + (size_t)(b * Nt + n) * C3 + nh * HDd;
        half8 q8[8];
#pragma unroll
        for (int c = 0; c < 8; ++c) q8[c] = ((const half8*)qp)[c];

        float m = -INFINITY, l = 0.f;
        float4 O4[16] = {};

        for (int j = 0; j <= Hs; ++j) {
            const half8* kp = (const half8*)&Kh[j * HDd];
            float s0 = 0.f, s1 = 0.f, s2 = 0.f, s3 = 0.f;
#pragma unroll
            for (int c = 0; c < 8; ++c) {
                half8 kk = kp[c];
                const half2_* k2 = (const half2_*)&kk;
                const half2_* qq = (const half2_*)&q8[c];
                s0 = fdot2f(qq[0], k2[0], s0);
                s1 = fdot2f(qq[1], k2[1], s1);
                s2 = fdot2f(qq[2], k2[2], s2);
                s3 = fdot2f(qq[3], k2[3], s3);
            }
            float s = ((s0 + s1) + (s2 + s3)) * SCALE;
            float mn = fmaxf(m, s);
            float corr = __expf(m - mn);
            float p = __expf(s - mn);
            l = l * corr + p;
            const float4* vp = (const float4*)&Vf[j * HDd];
#pragma unroll
            for (int d4 = 0; d4 < 16; ++d4) {
                float4 vv = vp[d4];
                O4[d4].x = fmaf(O4[d4].x, corr, p * vv.x);
                O4[d4].y = fmaf(O4[d4].y, corr, p * vv.y);
                O4[d4].z = fmaf(O4[d4].z, corr, p * vv.z);
                O4[d4].w = fmaf(O4[d4].w, corr, p * vv.w);
            }
            m = mn;
        }
        const size_t qi = (size_t)((b * NHh + nh) * HW_ + h * Ws + w);
        mcol[qi] = m;
        lcol[qi] = l;
#pragma unroll
        for (int d4 = 0; d4 < 16; ++d4)
            *(float4*)&Ocol[qi * HDd + d4 * 4] = O4[d4];
    }
}

// ---------------------------------------------------------------------------
// Row attention + merge -> attH (fp16)
// ---------------------------------------------------------------------------
__global__ __launch_bounds__(64) void row_attn_merge(
    const _Float16* __restrict__ qkvh, const float* __restrict__ Ocol,
    const float* __restrict__ mcol, const float* __restrict__ lcol,
    _Float16* __restrict__ attH)
{
    const int h = blockIdx.x, nh = blockIdx.y, b = blockIdx.z;
    __shared__ __align__(16) _Float16 Kh[Ws * HDd];
    __shared__ float Vf[Ws * HDd];
    const int tid = threadIdx.x;

    for (int e = tid; e < Ws * 8; e += 64) {
        int j = e >> 3, c = e & 7;
        int n = h * Ws + j + 1;
        const _Float16* base = qkvh + (size_t)(b * Nt + n) * C3 + nh * HDd + c * 8;
        *(half8*)&Kh[j * HDd + c * 8] = *(const half8*)(base + Cc);
        half8 vv = *(const half8*)(base + 2 * Cc);
        float4 lo = { (float)vv[0], (float)vv[1], (float)vv[2], (float)vv[3] };
        float4 hi = { (float)vv[4], (float)vv[5], (float)vv[6], (float)vv[7] };
        *(float4*)&Vf[j * HDd + c * 8] = lo;
        *(float4*)&Vf[j * HDd + c * 8 + 4] = hi;
    }
    __syncthreads();

    if (tid < Ws) {
        const int w = tid;
        const int n = h * Ws + w + 1;
        const _Float16* qp = qkvh + (size_t)(b * Nt + n) * C3 + nh * HDd;
        half8 q8[8];
#pragma unroll
        for (int c = 0; c < 8; ++c) q8[c] = ((const half8*)qp)[c];

        float m = -INFINITY, l = 0.f;
        float4 O4[16] = {};

        for (int j = 0; j < Ws; ++j) {
            if (j == w) continue;
            const half8* kp = (const half8*)&Kh[j * HDd];
            float s0 = 0.f, s1 = 0.f, s2 = 0.f, s3 = 0.f;
#pragma unroll
            for (int c = 0; c < 8; ++c) {
                half8 kk = kp[c];
                const half2_* k2 = (const half2_*)&kk;
                const half2_* qq = (const half2_*)&q8[c];
                s0 = fdot2f(qq[0], k2[0], s0);
                s1 = fdot2f(qq[1], k2[1], s1);
                s2 = fdot2f(qq[2], k2[2], s2);
                s3 = fdot2f(qq[3], k2[3], s3);
            }
            float s = ((s0 + s1) + (s2 + s3)) * SCALE;
            float mn = fmaxf(m, s);
            float corr = __expf(m - mn);
            float p = __expf(s - mn);
            l = l * corr + p;
            const float4* vp = (const float4*)&Vf[j * HDd];
#pragma unroll
            for (int d4 = 0; d4 < 16; ++d4) {
                float4 vv = vp[d4];
                O4[d4].x = fmaf(O4[d4].x, corr, p * vv.x);
                O4[d4].y = fmaf(O4[d4].y, corr, p * vv.y);
                O4[d4].z = fmaf(O4[d4].z, corr, p * vv.z);
                O4[d4].w = fmaf(O4[d4].w, corr, p * vv.w);
            }
            m = mn;
        }

        const size_t qi = (size_t)((b * NHh + nh) * HW_ + h * Ws + w);
        const float mc = mcol[qi], lc = lcol[qi];
        const float mn = fmaxf(mc, m);
        const float fc = __expf(mc - mn);
        const float fr = __expf(m - mn);
        const float inv = 1.f / (lc * fc + l * fr);
        _Float16* op = attH + (size_t)(b * Nt + n) * Cc + nh * HDd;
        const float* ocp = Ocol + qi * HDd;
#pragma unroll
        for (int d4 = 0; d4 < 16; ++d4) {
            float4 oc = *(const float4*)(ocp + d4 * 4);
            half4 r = { (_Float16)((oc.x * fc + O4[d4].x * fr) * inv),
                        (_Float16)((oc.y * fc + O4[d4].y * fr) * inv),
                        (_Float16)((oc.z * fc + O4[d4].z * fr) * inv),
                        (_Float16)((oc.w * fc + O4[d4].w * fr) * inv) };
            *(half4*)(op + d4 * 4) = r;
        }
    }
}

// ---------------------------------------------------------------------------
// Cls-token attention, 4-way key-split for occupancy. Partial (m,l,O) per
// (b,nh,s); merged by cls_merge.
// ---------------------------------------------------------------------------
__global__ __launch_bounds__(1024) void cls_part(
    const _Float16* __restrict__ qkvh, float* __restrict__ P)
{
    const int nh = blockIdx.x, b = blockIdx.y, sidx = blockIdx.z;
    const int j0 = sidx * 785, j1 = min(Nt, j0 + 785);
    const int tid = threadIdx.x;
    const int lane = tid & 63, wv = tid >> 6;

    const float qd = (float)qkvh[(size_t)(b * Nt) * C3 + nh * HDd + lane];
    float m = -INFINITY, l = 0.f, Od = 0.f;

    for (int j = j0 + wv; j < j1; j += 16) {
        const _Float16* base = qkvh + (size_t)(b * Nt + j) * C3 + nh * HDd;
        float prod = qd * (float)base[Cc + lane];
#pragma unroll
        for (int off = 32; off >= 1; off >>= 1)
            prod += __shfl_xor(prod, off, 64);
        float s = prod * SCALE;
        float mn = fmaxf(m, s);
        float corr = __expf(m - mn);
        float p = __expf(s - mn);
        l = l * corr + p;
        Od = fmaf(Od, corr, p * (float)base[2 * Cc + lane]);
        m = mn;
    }

    __shared__ float sm[16], sl[16], sO[16][64];
    if (lane == 0) { sm[wv] = m; sl[wv] = l; }
    sO[wv][lane] = Od;
    __syncthreads();

    if (tid < 64) {
        float M2 = sm[0];
#pragma unroll
        for (int i = 1; i < 16; ++i) M2 = fmaxf(M2, sm[i]);
        float L = 0.f, OO = 0.f;
#pragma unroll
        for (int i = 0; i < 16; ++i) {
            float f = __expf(sm[i] - M2);
            L += sl[i] * f;
            OO += sO[i][tid] * f;
        }
        float* pp = P + (size_t)((b * NHh + nh) * 4 + sidx) * 66;
        if (tid == 0) { pp[0] = M2; pp[1] = L; }
        pp[2 + tid] = OO;
    }
}

__global__ __launch_bounds__(64) void cls_merge(
    const float* __restrict__ P, _Float16* __restrict__ attH)
{
    const int nh = blockIdx.x, b = blockIdx.y;
    const int tid = threadIdx.x;
    const float* p0 = P + (size_t)(b * NHh + nh) * 4 * 66;
    float M2 = fmaxf(fmaxf(p0[0], p0[66]), fmaxf(p0[132], p0[198]));
    float L = 0.f, OO = 0.f;
#pragma unroll
    for (int i = 0; i < 4; ++i) {
        const float* pp = p0 + i * 66;
        float f = __expf(pp[0] - M2);
        L += pp[1] * f;
        OO += pp[2 + tid] * f;
    }
    attH[(size_t)(b * Nt) * Cc + nh * HDd + tid] = (_Float16)(OO / L);
}

// ---------------------------------------------------------------------------
extern "C" void kernel_launch(void* const* d_in, const int* in_sizes, int n_in,
                              void* d_out, int out_size, void* d_ws, size_t ws_size,
                              hipStream_t stream)
{
    const float* x     = (const float*)d_in[0];
    const float* Wqkv  = (const float*)d_in[1];
    const float* Wproj = (const float*)d_in[2];
    const float* bproj = (const float*)d_in[3];
    float* out = (float*)d_out;

    _Float16* qkvh;   hipGetSymbolAddress((void**)&qkvh,   HIP_SYMBOL(g_qkvh));
    float*    Ocol;   hipGetSymbolAddress((void**)&Ocol,   HIP_SYMBOL(g_Ocol));
    float*    mcol;   hipGetSymbolAddress((void**)&mcol,   HIP_SYMBOL(g_mcol));
    float*    lcol;   hipGetSymbolAddress((void**)&lcol,   HIP_SYMBOL(g_lcol));
    _Float16* xh;     hipGetSymbolAddress((void**)&xh,     HIP_SYMBOL(g_xh));
    _Float16* attH;   hipGetSymbolAddress((void**)&attH,   HIP_SYMBOL(g_attH));
    _Float16* WqkvT;  hipGetSymbolAddress((void**)&WqkvT,  HIP_SYMBOL(g_WqkvT));
    _Float16* WprojT; hipGetSymbolAddress((void**)&WprojT, HIP_SYMBOL(g_WprojT));
    float*    clsP;   hipGetSymbolAddress((void**)&clsP,   HIP_SYMBOL(g_clsP));

    // 0) prep
    cvt_f16<<<4096, 256, 0, stream>>>(x, xh, (Mrows * Cc) / 4);
    transpose_f16<<<dim3(C3 / 32, Cc / 32), 256, 0, stream>>>(Wqkv, WqkvT, Cc, C3);
    transpose_f16<<<dim3(Cc / 32, Cc / 32), 256, 0, stream>>>(Wproj, WprojT, Cc, Cc);

    // 1) qkv = x @ W_qkv  (fp16 out)
    gemm_f16<_Float16><<<dim3(C3 / 256, Mpad / 256), 512, 0, stream>>>(
        xh, WqkvT, nullptr, qkvh, Mrows, C3, Cc);

    // 2) attention
    col_attn<<<dim3(Ws, NHh, B_), 64, 0, stream>>>(qkvh, Ocol, mcol, lcol);
    cls_part<<<dim3(NHh, B_, 4), 1024, 0, stream>>>(qkvh, clsP);
    cls_merge<<<dim3(NHh, B_), 64, 0, stream>>>(clsP, attH);
    row_attn_merge<<<dim3(Hs, NHh, B_), 64, 0, stream>>>(qkvh, Ocol, mcol, lcol, attH);

    // 3) out = attH @ W_proj + b_proj  (fp32 out)
    gemm_f16<float><<<dim3(Cc / 256, Mpad / 256), 512, 0, stream>>>(
        attH, WprojT, bproj, out, Mrows, Cc, Cc);
}

// Round 3
// 630.946 us; speedup vs baseline: 1.1313x; 1.0076x over previous
//
#include <hip/hip_runtime.h>
#include <math.h>

#define B_   8
#define Hs   56
#define Ws   56
#define Cc   768
#define NHh  12
#define HDd  64
#define Nt   3137
#define HW_  3136
#define C3   2304
#define SCALE 0.125f
#define Mrows (B_ * Nt)        // 25096
#define Mpad  (99 * 256)       // 25344 (multiple of 256 and 128)

typedef _Float16 half8  __attribute__((ext_vector_type(8)));
typedef _Float16 half4  __attribute__((ext_vector_type(4)));
typedef _Float16 half2_ __attribute__((ext_vector_type(2)));
typedef float floatx4 __attribute__((ext_vector_type(4)));

#define WAITV(N) asm volatile("s_waitcnt vmcnt(" #N ")" ::: "memory")
#define WAITL    asm volatile("s_waitcnt lgkmcnt(0)" ::: "memory")

__device__ __forceinline__ void barrier_mem() {
    asm volatile("" ::: "memory");
    __builtin_amdgcn_s_barrier();
    asm volatile("" ::: "memory");
}

__device__ inline float fdot2f(half2_ a, half2_ b, float c) {
#if __has_builtin(__builtin_amdgcn_fdot2)
    return __builtin_amdgcn_fdot2(a, b, c, false);
#else
    return fmaf((float)a.x, (float)b.x, fmaf((float)a.y, (float)b.y, c));
#endif
}

__device__ __forceinline__ void gload_lds16(const _Float16* g, _Float16* l) {
    __builtin_amdgcn_global_load_lds(
        (const __attribute__((address_space(1))) void*)g,
        (__attribute__((address_space(3))) void*)l, 16, 0, 0);
}

// ---------------- scratch (__device__ globals) -----------------------------
__device__ _Float16 g_qkvh[(size_t)Mrows * C3];          // fp16 qkv (115 MB)
__device__ float    g_Ocol[(size_t)B_ * NHh * HW_ * HDd];
__device__ float    g_mcol[(size_t)B_ * NHh * HW_];
__device__ float    g_lcol[(size_t)B_ * NHh * HW_];
__device__ _Float16 g_xh[(size_t)Mpad * Cc];
__device__ _Float16 g_attH[(size_t)Mpad * Cc];
__device__ _Float16 g_WqkvT[(size_t)C3 * Cc];
__device__ _Float16 g_WprojT[(size_t)Cc * Cc];
__device__ float    g_clsP[(size_t)B_ * NHh * 4 * 66];   // per-partial: m,l,O[64]

// ---------------- fp32 -> fp16 convert -------------------------------------
__global__ __launch_bounds__(256) void cvt_f16(
    const float* __restrict__ in, _Float16* __restrict__ out, int n4)
{
    for (int i = blockIdx.x * 256 + threadIdx.x; i < n4; i += gridDim.x * 256) {
        float4 v = ((const float4*)in)[i];
        half4 h = { (_Float16)v.x, (_Float16)v.y, (_Float16)v.z, (_Float16)v.w };
        ((half4*)out)[i] = h;
    }
}

// ---------------- fp32 [R][Cq] -> fp16 transposed [Cq][R] ------------------
__global__ __launch_bounds__(256) void transpose_f16(
    const float* __restrict__ in, _Float16* __restrict__ out, int R, int Cq)
{
    __shared__ float t[32][33];
    const int c0 = blockIdx.x * 32, r0 = blockIdx.y * 32;
    const int tx = threadIdx.x & 31, ty = threadIdx.x >> 5;
#pragma unroll
    for (int i = 0; i < 32; i += 8)
        t[ty + i][tx] = in[(size_t)(r0 + ty + i) * Cq + c0 + tx];
    __syncthreads();
#pragma unroll
    for (int i = 0; i < 32; i += 8)
        out[(size_t)(c0 + ty + i) * R + r0 + tx] = (_Float16)t[tx][ty + i];
}

// ---------------------------------------------------------------------------
// fp16 MFMA GEMM: C[M,Nd] = A[Mpad,K] @ Bt[Nd,K]^T (+bias).
// R3: 8-phase schedule (T3+T4+T5). BMxBN=BMx256 tile, BK=64, 512 thr
// (8 waves 2Mx4N, per-wave out (BM/2)x64). TWO LDS dbufs; staging granularity
// = half-tile (half the rows of one matrix x 64k). Per K-tile, 4 phases:
//   q0: stage A-lo(t+1); vmcnt(LA) [counted, NOT 0]; barrier;
//       ds-read b@kk0 + a-lo@kk0; lgkm0; setprio1; 16 MFMA; setprio0; barrier
//   q1: stage A-hi(t+1); ds-read a-hi@kk0; lgkm0; MFMA(hi); barrier
//   q2: stage B-lo(t+1); ds-read b@kk1 + a-lo@kk1; lgkm0; MFMA; barrier
//   q3: stage B-hi(t+1); ds-read a-hi@kk1; lgkm0; MFMA(hi); barrier
// Race-freedom: stages during tile t only touch dbuf(t+1) != dbuf(t); the
// dbuf(t+1)=dbuf(t-1) reads were drained by every wave's lgkm0 + the barrier
// ending tile t-1. vmcnt waits only once per K-tile, with the next stage
// already in flight (steady state 2-10 loads across barriers).
// Epilogue: acc -> LDS (stride 140 dwords: 16B-aligned, conflict-light) ->
// fully-coalesced 16B/lane row stores. 16-row panel swizzle for L2 reuse.
// ---------------------------------------------------------------------------
template <typename OutT, int BM>
__global__ __launch_bounds__(512, 2) void gemm_f16(
    const _Float16* __restrict__ A, const _Float16* __restrict__ Bt,
    const float* __restrict__ bias, OutT* __restrict__ Cm,
    int M, int Nd, int K)
{
    constexpr int MI   = BM / 32;        // acc rows per wave (8 or 4)
    constexpr int MIH  = MI / 2;
    constexpr int LA   = BM / 128;       // loads/thread per A half-tile (2 or 1)
    constexpr int ASZh = BM * 64;        // halfs per A K-tile buffer
    constexpr int BSZh = 256 * 64;       // halfs per B K-tile buffer
    constexpr size_t MAINB = (size_t)2 * (ASZh + BSZh) * 2;
    constexpr size_t EPIB  = sizeof(OutT) == 2 ? (size_t)BM * 280 * 2
                                               : (size_t)BM * 140 * 4;
    constexpr size_t SMEMB = MAINB > EPIB ? MAINB : EPIB;
    __shared__ __align__(16) char smem[SMEMB];

    const int tid = threadIdx.x;
    const int wave = tid >> 6, lane = tid & 63;
    const int wm = wave & 1, wn = wave >> 1;

    // panel swizzle: 16 row-blocks per panel, col-major within panel
    const int bid = blockIdx.y * gridDim.x + blockIdx.x;
    const int perPanel = gridDim.x * 16;
    const int panel = bid / perPanel;
    const int rowsIn = min(16, (int)gridDim.y - panel * 16);
    const int rem = bid - panel * perPanel;
    const int by = panel * 16 + rem % rowsIn;
    const int bx = rem / rowsIn;
    const int mBase = by * BM, nBase = bx * 256;

    // staging geometry: unit u (16B) of a K-tile buffer holds
    // row = ((u>>7)<<4) + (u&15), kc = (u>>4)&7, at LDS byte offset u*16.
    // Thread's slice: u = j*512 + tid  (wave-uniform base + lane*16 => DMA ok)
    const int rU  = ((tid >> 7) << 4) + (tid & 15);
    const int kcU = (tid >> 4) & 7;

    auto stageHalf = [&](int kt, int h) {
        _Float16* arena = (_Float16*)smem + (size_t)(kt & 1) * (ASZh + BSZh);
        if (h < 2) {
            _Float16* ldsA = arena + h * (ASZh / 2) + tid * 8;
            const _Float16* g = A + (size_t)(mBase + h * (BM / 2) + rU) * K
                                  + kt * 64 + kcU * 8;
#pragma unroll
            for (int j = 0; j < LA; ++j)
                gload_lds16(g + (size_t)j * 64 * K, ldsA + j * 4096);
        } else {
            const int hh = h - 2;
            _Float16* ldsB = arena + ASZh + hh * (BSZh / 2) + tid * 8;
            const _Float16* g = Bt + (size_t)(nBase + hh * 128 + rU) * K
                                   + kt * 64 + kcU * 8;
#pragma unroll
            for (int j = 0; j < 2; ++j)
                gload_lds16(g + (size_t)j * 64 * K, ldsB + j * 4096);
        }
    };

    // fragment read: group g (16 rows) = g*1024 halfs; within: kk*512 +
    // (lane>>4)*128 + (lane&15)*8  (contiguous 1KB per wave -> conflict-free)
    const int fo = (lane >> 4) * 128 + (lane & 15) * 8;

    floatx4 acc[MI][4] = {};
    half8 a[MIH], b[4];

    const int NT = K >> 6;               // 12 K-tiles of 64
    stageHalf(0, 0); stageHalf(0, 1); stageHalf(0, 2); stageHalf(0, 3);

    for (int t = 0; t < NT; ++t) {
        const _Float16* aA = (const _Float16*)smem
                             + (size_t)(t & 1) * (ASZh + BSZh);
        const _Float16* aB = aA + ASZh;
        const bool st = (t + 1 < NT);

        // ---- q0: kk=0, mi-lo ----
        if (st) stageHalf(t + 1, 0);
        if (!st) { WAITV(0); }
        else if constexpr (LA == 2) { WAITV(2); }
        else { WAITV(1); }
        barrier_mem();
#pragma unroll
        for (int ni = 0; ni < 4; ++ni)
            b[ni] = *(const half8*)&aB[(wn * 4 + ni) * 1024 + fo];
#pragma unroll
        for (int mi = 0; mi < MIH; ++mi)
            a[mi] = *(const half8*)&aA[(wm * MI + mi) * 1024 + fo];
        WAITL;
        __builtin_amdgcn_s_setprio(1);
#pragma unroll
        for (int mi = 0; mi < MIH; ++mi)
#pragma unroll
            for (int ni = 0; ni < 4; ++ni)
                acc[mi][ni] = __builtin_amdgcn_mfma_f32_16x16x32_f16(
                    b[ni], a[mi], acc[mi][ni], 0, 0, 0);
        __builtin_amdgcn_s_setprio(0);
        barrier_mem();

        // ---- q1: kk=0, mi-hi ----
        if (st) stageHalf(t + 1, 1);
#pragma unroll
        for (int mi = 0; mi < MIH; ++mi)
            a[mi] = *(const half8*)&aA[(wm * MI + MIH + mi) * 1024 + fo];
        WAITL;
        __builtin_amdgcn_s_setprio(1);
#pragma unroll
        for (int mi = 0; mi < MIH; ++mi)
#pragma unroll
            for (int ni = 0; ni < 4; ++ni)
                acc[MIH + mi][ni] = __builtin_amdgcn_mfma_f32_16x16x32_f16(
                    b[ni], a[mi], acc[MIH + mi][ni], 0, 0, 0);
        __builtin_amdgcn_s_setprio(0);
        barrier_mem();

        // ---- q2: kk=1, mi-lo ----
        if (st) stageHalf(t + 1, 2);
#pragma unroll
        for (int ni = 0; ni < 4; ++ni)
            b[ni] = *(const half8*)&aB[(wn * 4 + ni) * 1024 + 512 + fo];
#pragma unroll
        for (int mi = 0; mi < MIH; ++mi)
            a[mi] = *(const half8*)&aA[(wm * MI + mi) * 1024 + 512 + fo];
        WAITL;
        __builtin_amdgcn_s_setprio(1);
#pragma unroll
        for (int mi = 0; mi < MIH; ++mi)
#pragma unroll
            for (int ni = 0; ni < 4; ++ni)
                acc[mi][ni] = __builtin_amdgcn_mfma_f32_16x16x32_f16(
                    b[ni], a[mi], acc[mi][ni], 0, 0, 0);
        __builtin_amdgcn_s_setprio(0);
        barrier_mem();

        // ---- q3: kk=1, mi-hi ----
        if (st) stageHalf(t + 1, 3);
#pragma unroll
        for (int mi = 0; mi < MIH; ++mi)
            a[mi] = *(const half8*)&aA[(wm * MI + MIH + mi) * 1024 + 512 + fo];
        WAITL;
        __builtin_amdgcn_s_setprio(1);
#pragma unroll
        for (int mi = 0; mi < MIH; ++mi)
#pragma unroll
            for (int ni = 0; ni < 4; ++ni)
                acc[MIH + mi][ni] = __builtin_amdgcn_mfma_f32_16x16x32_f16(
                    b[ni], a[mi], acc[MIH + mi][ni], 0, 0, 0);
        __builtin_amdgcn_s_setprio(0);
        barrier_mem();     // end of tile: all reads of dbuf(t) drained
    }

    // -------- epilogue: LDS bounce, stride 140 dwords --------
    const int mlBase = wm * (BM / 2) + (lane & 15);
    const int nlBase = wn * 64 + ((lane >> 4) << 2);

    if constexpr (sizeof(OutT) == 2) {
        _Float16* Ch = (_Float16*)smem;          // [BM][280] halfs
#pragma unroll
        for (int ni = 0; ni < 4; ++ni) {
            const int nl = nlBase + ni * 16;
#pragma unroll
            for (int mi = 0; mi < MI; ++mi) {
                const int ml = mlBase + mi * 16;
                floatx4 v = acc[mi][ni];
                half4 h = { (_Float16)v[0], (_Float16)v[1],
                            (_Float16)v[2], (_Float16)v[3] };
                *(half4*)&Ch[ml * 280 + nl] = h;
            }
        }
        barrier_mem();
#pragma unroll
        for (int i = 0; i < BM / 16; ++i) {
            const int f = i * 512 + tid;
            const int row = f >> 5, u = f & 31;
            const int gm = mBase + row;
            if (gm < M)
                *(half8*)&Cm[(size_t)gm * Nd + nBase + u * 8] =
                    *(const half8*)&Ch[row * 280 + u * 8];
        }
    } else {
        float* Cf = (float*)smem;                // [BM][140] floats
#pragma unroll
        for (int nh = 0; nh < 2; ++nh) {
            barrier_mem();                       // prev pass reads done
            if ((wn >> 1) == nh) {
#pragma unroll
                for (int ni = 0; ni < 4; ++ni) {
                    const int n0 = nBase + wn * 64 + ((lane >> 4) << 2) + ni * 16;
                    float4 bv = bias ? *(const float4*)&bias[n0]
                                     : make_float4(0.f, 0.f, 0.f, 0.f);
                    const int nl = (wn & 1) * 64 + ((lane >> 4) << 2) + ni * 16;
#pragma unroll
                    for (int mi = 0; mi < MI; ++mi) {
                        const int ml = mlBase + mi * 16;
                        floatx4 v = acc[mi][ni];
                        float4 o = make_float4(v[0] + bv.x, v[1] + bv.y,
                                               v[2] + bv.z, v[3] + bv.w);
                        *(float4*)&Cf[ml * 140 + nl] = o;
                    }
                }
            }
            barrier_mem();
#pragma unroll
            for (int i = 0; i < BM / 16; ++i) {
                const int f = i * 512 + tid;
                const int row = f >> 5, u = f & 31;
                const int gm = mBase + row;
                if (gm < M)
                    *(float4*)&Cm[(size_t)gm * Nd + nBase + nh * 128 + u * 4] =
                        *(const float4*)&Cf[row * 140 + u * 4];
            }
        }
    }
}

// ---------------------------------------------------------------------------
// Column attention partials: block (w,nh,b), 64 thr. K fp16 LDS + fdot2,
// V fp32 LDS. Online softmax, unnormalized partial out.
// ---------------------------------------------------------------------------
__global__ __launch_bounds__(64) void col_attn(
    const _Float16* __restrict__ qkvh, float* __restrict__ Ocol,
    float* __restrict__ mcol, float* __restrict__ lcol)
{
    const int w = blockIdx.x, nh = blockIdx.y, b = blockIdx.z;
    __shared__ __align__(16) _Float16 Kh[57 * HDd];
    __shared__ float Vf[57 * HDd];
    const int tid = threadIdx.x;

    for (int e = tid; e < 57 * 8; e += 64) {
        int j = e >> 3, c = e & 7;
        int n = (j == 0) ? 0 : ((j - 1) * Ws + w + 1);
        const _Float16* base = qkvh + (size_t)(b * Nt + n) * C3 + nh * HDd + c * 8;
        *(half8*)&Kh[j * HDd + c * 8] = *(const half8*)(base + Cc);
        half8 vv = *(const half8*)(base + 2 * Cc);
        float4 lo = { (float)vv[0], (float)vv[1], (float)vv[2], (float)vv[3] };
        float4 hi = { (float)vv[4], (float)vv[5], (float)vv[6], (float)vv[7] };
        *(float4*)&Vf[j * HDd + c * 8] = lo;
        *(float4*)&Vf[j * HDd + c * 8 + 4] = hi;
    }
    __syncthreads();

    if (tid < Hs) {
        const int h = tid;
        const int n = h * Ws + w + 1;
        const _Float16* qp = qkvh + (size_t)(b * Nt + n) * C3 + nh * HDd;
        half8 q8[8];
#pragma unroll
        for (int c = 0; c < 8; ++c) q8[c] = ((const half8*)qp)[c];

        float m = -INFINITY, l = 0.f;
        float4 O4[16] = {};

        for (int j = 0; j <= Hs; ++j) {
            const half8* kp = (const half8*)&Kh[j * HDd];
            float s0 = 0.f, s1 = 0.f, s2 = 0.f, s3 = 0.f;
#pragma unroll
            for (int c = 0; c < 8; ++c) {
                half8 kk = kp[c];
                const half2_* k2 = (const half2_*)&kk;
                const half2_* qq = (const half2_*)&q8[c];
                s0 = fdot2f(qq[0], k2[0], s0);
                s1 = fdot2f(qq[1], k2[1], s1);
                s2 = fdot2f(qq[2], k2[2], s2);
                s3 = fdot2f(qq[3], k2[3], s3);
            }
            float s = ((s0 + s1) + (s2 + s3)) * SCALE;
            float mn = fmaxf(m, s);
            float corr = __expf(m - mn);
            float p = __expf(s - mn);
            l = l * corr + p;
            const float4* vp = (const float4*)&Vf[j * HDd];
#pragma unroll
            for (int d4 = 0; d4 < 16; ++d4) {
                float4 vv = vp[d4];
                O4[d4].x = fmaf(O4[d4].x, corr, p * vv.x);
                O4[d4].y = fmaf(O4[d4].y, corr, p * vv.y);
                O4[d4].z = fmaf(O4[d4].z, corr, p * vv.z);
                O4[d4].w = fmaf(O4[d4].w, corr, p * vv.w);
            }
            m = mn;
        }
        const size_t qi = (size_t)((b * NHh + nh) * HW_ + h * Ws + w);
        mcol[qi] = m;
        lcol[qi] = l;
#pragma unroll
        for (int d4 = 0; d4 < 16; ++d4)
            *(float4*)&Ocol[qi * HDd + d4 * 4] = O4[d4];
    }
}

// ---------------------------------------------------------------------------
// Row attention + merge -> attH (fp16)
// ---------------------------------------------------------------------------
__global__ __launch_bounds__(64) void row_attn_merge(
    const _Float16* __restrict__ qkvh, const float* __restrict__ Ocol,
    const float* __restrict__ mcol, const float* __restrict__ lcol,
    _Float16* __restrict__ attH)
{
    const int h = blockIdx.x, nh = blockIdx.y, b = blockIdx.z;
    __shared__ __align__(16) _Float16 Kh[Ws * HDd];
    __shared__ float Vf[Ws * HDd];
    const int tid = threadIdx.x;

    for (int e = tid; e < Ws * 8; e += 64) {
        int j = e >> 3, c = e & 7;
        int n = h * Ws + j + 1;
        const _Float16* base = qkvh + (size_t)(b * Nt + n) * C3 + nh * HDd + c * 8;
        *(half8*)&Kh[j * HDd + c * 8] = *(const half8*)(base + Cc);
        half8 vv = *(const half8*)(base + 2 * Cc);
        float4 lo = { (float)vv[0], (float)vv[1], (float)vv[2], (float)vv[3] };
        float4 hi = { (float)vv[4], (float)vv[5], (float)vv[6], (float)vv[7] };
        *(float4*)&Vf[j * HDd + c * 8] = lo;
        *(float4*)&Vf[j * HDd + c * 8 + 4] = hi;
    }
    __syncthreads();

    if (tid < Ws) {
        const int w = tid;
        const int n = h * Ws + w + 1;
        const _Float16* qp = qkvh + (size_t)(b * Nt + n) * C3 + nh * HDd;
        half8 q8[8];
#pragma unroll
        for (int c = 0; c < 8; ++c) q8[c] = ((const half8*)qp)[c];

        float m = -INFINITY, l = 0.f;
        float4 O4[16] = {};

        for (int j = 0; j < Ws; ++j) {
            if (j == w) continue;
            const half8* kp = (const half8*)&Kh[j * HDd];
            float s0 = 0.f, s1 = 0.f, s2 = 0.f, s3 = 0.f;
#pragma unroll
            for (int c = 0; c < 8; ++c) {
                half8 kk = kp[c];
                const half2_* k2 = (const half2_*)&kk;
                const half2_* qq = (const half2_*)&q8[c];
                s0 = fdot2f(qq[0], k2[0], s0);
                s1 = fdot2f(qq[1], k2[1], s1);
                s2 = fdot2f(qq[2], k2[2], s2);
                s3 = fdot2f(qq[3], k2[3], s3);
            }
            float s = ((s0 + s1) + (s2 + s3)) * SCALE;
            float mn = fmaxf(m, s);
            float corr = __expf(m - mn);
            float p = __expf(s - mn);
            l = l * corr + p;
            const float4* vp = (const float4*)&Vf[j * HDd];
#pragma unroll
            for (int d4 = 0; d4 < 16; ++d4) {
                float4 vv = vp[d4];
                O4[d4].x = fmaf(O4[d4].x, corr, p * vv.x);
                O4[d4].y = fmaf(O4[d4].y, corr, p * vv.y);
                O4[d4].z = fmaf(O4[d4].z, corr, p * vv.z);
                O4[d4].w = fmaf(O4[d4].w, corr, p * vv.w);
            }
            m = mn;
        }

        const size_t qi = (size_t)((b * NHh + nh) * HW_ + h * Ws + w);
        const float mc = mcol[qi], lc = lcol[qi];
        const float mn = fmaxf(mc, m);
        const float fc = __expf(mc - mn);
        const float fr = __expf(m - mn);
        const float inv = 1.f / (lc * fc + l * fr);
        _Float16* op = attH + (size_t)(b * Nt + n) * Cc + nh * HDd;
        const float* ocp = Ocol + qi * HDd;
#pragma unroll
        for (int d4 = 0; d4 < 16; ++d4) {
            float4 oc = *(const float4*)(ocp + d4 * 4);
            half4 r = { (_Float16)((oc.x * fc + O4[d4].x * fr) * inv),
                        (_Float16)((oc.y * fc + O4[d4].y * fr) * inv),
                        (_Float16)((oc.z * fc + O4[d4].z * fr) * inv),
                        (_Float16)((oc.w * fc + O4[d4].w * fr) * inv) };
            *(half4*)(op + d4 * 4) = r;
        }
    }
}

// ---------------------------------------------------------------------------
// Cls-token attention, 4-way key-split for occupancy. Partial (m,l,O) per
// (b,nh,s); merged by cls_merge.
// ---------------------------------------------------------------------------
__global__ __launch_bounds__(1024) void cls_part(
    const _Float16* __restrict__ qkvh, float* __restrict__ P)
{
    const int nh = blockIdx.x, b = blockIdx.y, sidx = blockIdx.z;
    const int j0 = sidx * 785, j1 = min(Nt, j0 + 785);
    const int tid = threadIdx.x;
    const int lane = tid & 63, wv = tid >> 6;

    const float qd = (float)qkvh[(size_t)(b * Nt) * C3 + nh * HDd + lane];
    float m = -INFINITY, l = 0.f, Od = 0.f;

    for (int j = j0 + wv; j < j1; j += 16) {
        const _Float16* base = qkvh + (size_t)(b * Nt + j) * C3 + nh * HDd;
        float prod = qd * (float)base[Cc + lane];
#pragma unroll
        for (int off = 32; off >= 1; off >>= 1)
            prod += __shfl_xor(prod, off, 64);
        float s = prod * SCALE;
        float mn = fmaxf(m, s);
        float corr = __expf(m - mn);
        float p = __expf(s - mn);
        l = l * corr + p;
        Od = fmaf(Od, corr, p * (float)base[2 * Cc + lane]);
        m = mn;
    }

    __shared__ float sm[16], sl[16], sO[16][64];
    if (lane == 0) { sm[wv] = m; sl[wv] = l; }
    sO[wv][lane] = Od;
    __syncthreads();

    if (tid < 64) {
        float M2 = sm[0];
#pragma unroll
        for (int i = 1; i < 16; ++i) M2 = fmaxf(M2, sm[i]);
        float L = 0.f, OO = 0.f;
#pragma unroll
        for (int i = 0; i < 16; ++i) {
            float f = __expf(sm[i] - M2);
            L += sl[i] * f;
            OO += sO[i][tid] * f;
        }
        float* pp = P + (size_t)((b * NHh + nh) * 4 + sidx) * 66;
        if (tid == 0) { pp[0] = M2; pp[1] = L; }
        pp[2 + tid] = OO;
    }
}

__global__ __launch_bounds__(64) void cls_merge(
    const float* __restrict__ P, _Float16* __restrict__ attH)
{
    const int nh = blockIdx.x, b = blockIdx.y;
    const int tid = threadIdx.x;
    const float* p0 = P + (size_t)(b * NHh + nh) * 4 * 66;
    float M2 = fmaxf(fmaxf(p0[0], p0[66]), fmaxf(p0[132], p0[198]));
    float L = 0.f, OO = 0.f;
#pragma unroll
    for (int i = 0; i < 4; ++i) {
        const float* pp = p0 + i * 66;
        float f = __expf(pp[0] - M2);
        L += pp[1] * f;
        OO += pp[2 + tid] * f;
    }
    attH[(size_t)(b * Nt) * Cc + nh * HDd + tid] = (_Float16)(OO / L);
}

// ---------------------------------------------------------------------------
extern "C" void kernel_launch(void* const* d_in, const int* in_sizes, int n_in,
                              void* d_out, int out_size, void* d_ws, size_t ws_size,
                              hipStream_t stream)
{
    const float* x     = (const float*)d_in[0];
    const float* Wqkv  = (const float*)d_in[1];
    const float* Wproj = (const float*)d_in[2];
    const float* bproj = (const float*)d_in[3];
    float* out = (float*)d_out;

    _Float16* qkvh;   hipGetSymbolAddress((void**)&qkvh,   HIP_SYMBOL(g_qkvh));
    float*    Ocol;   hipGetSymbolAddress((void**)&Ocol,   HIP_SYMBOL(g_Ocol));
    float*    mcol;   hipGetSymbolAddress((void**)&mcol,   HIP_SYMBOL(g_mcol));
    float*    lcol;   hipGetSymbolAddress((void**)&lcol,   HIP_SYMBOL(g_lcol));
    _Float16* xh;     hipGetSymbolAddress((void**)&xh,     HIP_SYMBOL(g_xh));
    _Float16* attH;   hipGetSymbolAddress((void**)&attH,   HIP_SYMBOL(g_attH));
    _Float16* WqkvT;  hipGetSymbolAddress((void**)&WqkvT,  HIP_SYMBOL(g_WqkvT));
    _Float16* WprojT; hipGetSymbolAddress((void**)&WprojT, HIP_SYMBOL(g_WprojT));
    float*    clsP;   hipGetSymbolAddress((void**)&clsP,   HIP_SYMBOL(g_clsP));

    // 0) prep
    cvt_f16<<<4096, 256, 0, stream>>>(x, xh, (Mrows * Cc) / 4);
    transpose_f16<<<dim3(C3 / 32, Cc / 32), 256, 0, stream>>>(Wqkv, WqkvT, Cc, C3);
    transpose_f16<<<dim3(Cc / 32, Cc / 32), 256, 0, stream>>>(Wproj, WprojT, Cc, Cc);

    // 1) qkv = x @ W_qkv  (fp16 out), 256x256 tiles
    gemm_f16<_Float16, 256><<<dim3(C3 / 256, Mpad / 256), 512, 0, stream>>>(
        xh, WqkvT, nullptr, qkvh, Mrows, C3, Cc);

    // 2) attention
    col_attn<<<dim3(Ws, NHh, B_), 64, 0, stream>>>(qkvh, Ocol, mcol, lcol);
    cls_part<<<dim3(NHh, B_, 4), 1024, 0, stream>>>(qkvh, clsP);
    cls_merge<<<dim3(NHh, B_), 64, 0, stream>>>(clsP, attH);
    row_attn_merge<<<dim3(Hs, NHh, B_), 64, 0, stream>>>(qkvh, Ocol, mcol, lcol, attH);

    // 3) out = attH @ W_proj + b_proj  (fp32 out), 128x256 tiles (tail fix)
    gemm_f16<float, 128><<<dim3(Cc / 256, Mpad / 128), 512, 0, stream>>>(
        attH, WprojT, bproj, out, Mrows, Cc, Cc);
}